// Round 7
// baseline (245.572 us; speedup 1.0000x reference)
//
#include <hip/hip_runtime.h>
#include <math.h>

#define PI_F   3.14159265358979f
#define PIO32  0.0981747704246810f   // pi/32
#define REP 6

constexpr float CT[32] = {
  1.0f,          0.995184727f,  0.980785280f,  0.956940336f,
  0.923879533f,  0.881921264f,  0.831469612f,  0.773010453f,
  0.707106781f,  0.634393284f,  0.555570233f,  0.471396737f,
  0.382683432f,  0.290284677f,  0.195090322f,  0.0980171403f,
  0.0f,         -0.0980171403f, -0.195090322f, -0.290284677f,
 -0.382683432f, -0.471396737f, -0.555570233f, -0.634393284f,
 -0.707106781f, -0.773010453f, -0.831469612f, -0.881921264f,
 -0.923879533f, -0.956940336f, -0.980785280f, -0.995184727f };
constexpr float ST[32] = {
  0.0f,          0.0980171403f, 0.195090322f,  0.290284677f,
  0.382683432f,  0.471396737f,  0.555570233f,  0.634393284f,
  0.707106781f,  0.773010453f,  0.831469612f,  0.881921264f,
  0.923879533f,  0.956940336f,  0.980785280f,  0.995184727f,
  1.0f,          0.995184727f,  0.980785280f,  0.956940336f,
  0.923879533f,  0.881921264f,  0.831469612f,  0.773010453f,
  0.707106781f,  0.634393284f,  0.555570233f,  0.471396737f,
  0.382683432f,  0.290284677f,  0.195090322f,  0.0980171403f };

struct Dim {
  float K, Cr, Ci, sth, cth, spole;
  int   pstar;
};

__device__ inline Dim dimcalc(float sp) {
  Dim d;
  const float ps = rintf(sp);
  d.pstar = (int)ps;
  float dstar = sp - ps;                 // EXACT in fp32 (Sterbenz)
  if (dstar == 0.0f) dstar = 1e-10f;
  const float th = sp * PIO32;
  d.sth = __sinf(th);  d.cth = __cosf(th);
  const float pd = PI_F * dstar;
  const float sd = __sinf(pd);
  const float cd = __cosf(pd);
  const float par = (d.pstar & 1) ? -1.0f : 1.0f;
  d.K = par * sd;
  d.Cr = par * fmaf(cd, d.cth, sd * d.sth);
  d.Ci = par * fmaf(sd, d.cth, -cd * d.sth);
  const float x = dstar * PIO32;
  const float x2 = x * x;
  d.spole = x * fmaf(x2, fmaf(x2, 0.00833333333f, -0.166666667f), 1.0f);
  return d;
}

// ---- Variant A: 4 lanes/point (current structure), REP-looped ----
__global__ __launch_bounds__(256) void fi_repA(
    const float* __restrict__ y_, const float* __restrict__ xnew_,
    float* __restrict__ out_) {
  const float* y = y_; const float* xnew = xnew_; float* out = out_;
  const int tid = threadIdx.x;
  const int gid = blockIdx.x * 256 + tid;
  const int h  = gid & 3;
  const int pt = gid >> 2;
  const int b  = pt >> 12;
  const int l  = tid & 63;
  const int wbase = (blockIdx.x * 256 + (tid & ~63)) >> 2;

  for (int rep = 0; rep < REP; ++rep) {
    asm volatile("" : "+s"(y), "+s"(xnew), "+s"(out) :: "memory");
    const float2 x2v = ((const float2*)xnew)[pt];
    const Dim d0 = dimcalc(x2v.x * 31.0f);
    const Dim d1 = dimcalc(x2v.y * 31.0f);

    float Gr[32], Gi[32];
#pragma unroll
    for (int q = 0; q < 32; ++q) {
      float s = fmaf(d1.sth, CT[q], -d1.cth * ST[q]);
      if (q == d1.pstar) s = d1.spole;
      const float t = d1.K * __builtin_amdgcn_rcpf(s);
      Gr[q] = t * CT[q];  Gi[q] = t * ST[q];
    }

    const float e4r = (h == 0) ? 1.f : (h == 1) ? 0.707106781f
                    : (h == 2) ? 0.f : -0.707106781f;
    const float e4i = (h == 0) ? 0.f : (h == 1) ? 0.707106781f
                    : (h == 2) ? 1.f : 0.707106781f;
    const int p0 = h * 8;
    float Hr[8], Hi[8];
#pragma unroll
    for (int pp = 0; pp < 8; ++pp) {
      const float Tr = fmaf(e4r, CT[pp], -e4i * ST[pp]);
      const float Ti = fmaf(e4r, ST[pp],  e4i * CT[pp]);
      float s = fmaf(d0.sth, Tr, -d0.cth * Ti);
      if (p0 + pp == d0.pstar) s = d0.spole;
      const float t = d0.K * __builtin_amdgcn_rcpf(s);
      Hr[pp] = t * Tr;  Hi[pp] = t * Ti;
    }

    const float4* yr = (const float4*)(y + b * 1024 + p0 * 32);
    float Zr = 0.f, Zi = 0.f;
#pragma unroll 2
    for (int pp = 0; pp < 8; ++pp) {
      float SrA = 0.f, SrB = 0.f, SiA = 0.f, SiB = 0.f;
#pragma unroll
      for (int q4 = 0; q4 < 8; ++q4) {
        const float4 v = yr[pp * 8 + q4];
        SrA = fmaf(v.x, Gr[4*q4+0], SrA); SiA = fmaf(v.x, Gi[4*q4+0], SiA);
        SrB = fmaf(v.y, Gr[4*q4+1], SrB); SiB = fmaf(v.y, Gi[4*q4+1], SiB);
        SrA = fmaf(v.z, Gr[4*q4+2], SrA); SiA = fmaf(v.z, Gi[4*q4+2], SiA);
        SrB = fmaf(v.w, Gr[4*q4+3], SrB); SiB = fmaf(v.w, Gi[4*q4+3], SiB);
      }
      const float Sr = SrA + SrB, Si = SiA + SiB;
      Zr = fmaf(Hr[pp], Sr, Zr); Zr = fmaf(-Hi[pp], Si, Zr);
      Zi = fmaf(Hr[pp], Si, Zi); Zi = fmaf(Hi[pp], Sr, Zi);
    }

    Zr += __shfl_xor(Zr, 1); Zr += __shfl_xor(Zr, 2);
    Zi += __shfl_xor(Zi, 1); Zi += __shfl_xor(Zi, 2);
    const float Cr = fmaf(d0.Cr, d1.Cr, -d0.Ci * d1.Ci);
    const float Ci = fmaf(d0.Cr, d1.Ci,  d0.Ci * d1.Cr);
    const float res = fmaf(Cr, Zr, -Ci * Zi) * (1.0f / 1024.0f);
    const float packed = __shfl(res, (l & 15) * 4);
    if (l < 16) out[wbase + l] = packed;
  }
}

// ---- Variant B: 8 lanes/point (4 rows/lane, 4 waves/SIMD), REP-looped ----
__global__ __launch_bounds__(256) void fi_repB(
    const float* __restrict__ y_, const float* __restrict__ xnew_,
    float* __restrict__ out_) {
  const float* y = y_; const float* xnew = xnew_; float* out = out_;
  const int tid = threadIdx.x;
  const int gid = blockIdx.x * 256 + tid;
  const int h  = gid & 7;
  const int pt = gid >> 3;
  const int b  = pt >> 12;
  const int l  = tid & 63;
  const int wbase = (blockIdx.x * 256 + (tid & ~63)) >> 3;

  for (int rep = 0; rep < REP; ++rep) {
    asm volatile("" : "+s"(y), "+s"(xnew), "+s"(out) :: "memory");
    const float2 x2v = ((const float2*)xnew)[pt];
    const Dim d0 = dimcalc(x2v.x * 31.0f);
    const Dim d1 = dimcalc(x2v.y * 31.0f);

    float Gr[32], Gi[32];
#pragma unroll
    for (int q = 0; q < 32; ++q) {
      float s = fmaf(d1.sth, CT[q], -d1.cth * ST[q]);
      if (q == d1.pstar) s = d1.spole;
      const float t = d1.K * __builtin_amdgcn_rcpf(s);
      Gr[q] = t * CT[q];  Gi[q] = t * ST[q];
    }

    // e8 = cis(pi*h/8)
    const float ang = (float)h * (PI_F / 8.0f);
    const float e8r = __cosf(ang), e8i = __sinf(ang);
    const int p0 = h * 4;
    float Hr[4], Hi[4];
#pragma unroll
    for (int pp = 0; pp < 4; ++pp) {
      const float Tr = fmaf(e8r, CT[pp], -e8i * ST[pp]);
      const float Ti = fmaf(e8r, ST[pp],  e8i * CT[pp]);
      float s = fmaf(d0.sth, Tr, -d0.cth * Ti);
      if (p0 + pp == d0.pstar) s = d0.spole;
      const float t = d0.K * __builtin_amdgcn_rcpf(s);
      Hr[pp] = t * Tr;  Hi[pp] = t * Ti;
    }

    const float4* yr = (const float4*)(y + b * 1024 + p0 * 32);
    float Zr = 0.f, Zi = 0.f;
#pragma unroll 2
    for (int pp = 0; pp < 4; ++pp) {
      float SrA = 0.f, SrB = 0.f, SiA = 0.f, SiB = 0.f;
#pragma unroll
      for (int q4 = 0; q4 < 8; ++q4) {
        const float4 v = yr[pp * 8 + q4];
        SrA = fmaf(v.x, Gr[4*q4+0], SrA); SiA = fmaf(v.x, Gi[4*q4+0], SiA);
        SrB = fmaf(v.y, Gr[4*q4+1], SrB); SiB = fmaf(v.y, Gi[4*q4+1], SiB);
        SrA = fmaf(v.z, Gr[4*q4+2], SrA); SiA = fmaf(v.z, Gi[4*q4+2], SiA);
        SrB = fmaf(v.w, Gr[4*q4+3], SrB); SiB = fmaf(v.w, Gi[4*q4+3], SiB);
      }
      const float Sr = SrA + SrB, Si = SiA + SiB;
      Zr = fmaf(Hr[pp], Sr, Zr); Zr = fmaf(-Hi[pp], Si, Zr);
      Zi = fmaf(Hr[pp], Si, Zi); Zi = fmaf(Hi[pp], Sr, Zi);
    }

    Zr += __shfl_xor(Zr, 1); Zr += __shfl_xor(Zr, 2); Zr += __shfl_xor(Zr, 4);
    Zi += __shfl_xor(Zi, 1); Zi += __shfl_xor(Zi, 2); Zi += __shfl_xor(Zi, 4);
    const float Cr = fmaf(d0.Cr, d1.Cr, -d0.Ci * d1.Ci);
    const float Ci = fmaf(d0.Cr, d1.Ci,  d0.Ci * d1.Cr);
    const float res = fmaf(Cr, Zr, -Ci * Zi) * (1.0f / 1024.0f);
    const float packed = __shfl(res, (l & 7) * 8);
    if (l < 8) out[wbase + l] = packed;
  }
}

extern "C" void kernel_launch(void* const* d_in, const int* in_sizes, int n_in,
                              void* d_out, int out_size, void* d_ws, size_t ws_size,
                              hipStream_t stream) {
  const float* y    = (const float*)d_in[0];   // (8, 32, 32) f32
  const float* xnew = (const float*)d_in[1];   // (8, 64, 64, 2) f32
  float* out = (float*)d_out;                  // (8, 64, 64) f32
  (void)d_ws; (void)ws_size;

  // A: 32768 points * 4 lanes / 256 = 512 blocks.  B: * 8 lanes = 1024 blocks.
  // Both write identical values to out (B last; both correct).
  hipLaunchKernelGGL(fi_repA, dim3(512),  dim3(256), 0, stream, y, xnew, out);
  hipLaunchKernelGGL(fi_repB, dim3(1024), dim3(256), 0, stream, y, xnew, out);
}

// Round 12
// 68.810 us; speedup vs baseline: 3.5689x; 3.5689x over previous
//
#include <hip/hip_runtime.h>
#include <math.h>

#define PI_F   3.14159265358979f
#define PIO32  0.0981747704246810f   // pi/32

// cos(pi*k/32), sin(pi*k/32), k = 0..31. Only indexed with compile-time
// constants -> fold to instruction literals.
constexpr float CT[32] = {
  1.0f,          0.995184727f,  0.980785280f,  0.956940336f,
  0.923879533f,  0.881921264f,  0.831469612f,  0.773010453f,
  0.707106781f,  0.634393284f,  0.555570233f,  0.471396737f,
  0.382683432f,  0.290284677f,  0.195090322f,  0.0980171403f,
  0.0f,         -0.0980171403f, -0.195090322f, -0.290284677f,
 -0.382683432f, -0.471396737f, -0.555570233f, -0.634393284f,
 -0.707106781f, -0.773010453f, -0.831469612f, -0.881921264f,
 -0.923879533f, -0.956940336f, -0.980785280f, -0.995184727f };
constexpr float ST[32] = {
  0.0f,          0.0980171403f, 0.195090322f,  0.290284677f,
  0.382683432f,  0.471396737f,  0.555570233f,  0.634393284f,
  0.707106781f,  0.773010453f,  0.831469612f,  0.881921264f,
  0.923879533f,  0.956940336f,  0.980785280f,  0.995184727f,
  1.0f,          0.995184727f,  0.980785280f,  0.956940336f,
  0.923879533f,  0.881921264f,  0.831469612f,  0.773010453f,
  0.707106781f,  0.634393284f,  0.555570233f,  0.471396737f,
  0.382683432f,  0.290284677f,  0.195090322f,  0.0980171403f };

struct Dim {
  float K;         // (-1)^{p*} * sin(pi * dstar)
  float Cr, Ci;    // cis((31pi/32) * sp)
  float sth, cth;  // sincos((pi/32) * sp)
  float spole;     // accurate sin((pi/32) * dstar)
  int   pstar;     // nearest grid line
};

__device__ __forceinline__ Dim dimcalc(float sp) {
  Dim d;
  const float ps = rintf(sp);
  d.pstar = (int)ps;
  float dstar = sp - ps;                 // EXACT in fp32 (Sterbenz)
  if (dstar == 0.0f) dstar = 1e-10f;     // removable singularity: ratio -> 32
  const float th = sp * PIO32;           // |th| <= 31pi/32: HW sin range
  d.sth = __sinf(th);
  d.cth = __cosf(th);
  const float pd = PI_F * dstar;         // |pd| <= pi/2
  const float sd = __sinf(pd);
  const float cd = __cosf(pd);
  const float par = (d.pstar & 1) ? -1.0f : 1.0f;
  d.K = par * sd;
  d.Cr = par * fmaf(cd, d.cth, sd * d.sth);
  d.Ci = par * fmaf(sd, d.cth, -cd * d.sth);
  const float x = dstar * PIO32;
  const float x2 = x * x;
  d.spole = x * fmaf(x2, fmaf(x2, 0.00833333333f, -0.166666667f), 1.0f);
  return d;
}

// out[b,n] = (1/1024) * Re( C0*C1 * sum_p H_p sum_q y[p,q] G_q )
// 4 lanes/point; lane h owns rows p = 8h..8h+7.
//
// SCRATCH FIX (r7 counters: VGPR=76 => the 64-float G table lived in
// scratch; L1 thrash; VALUBusy 19%; 16us). This body has ZERO arrays:
// all 16 row accumulators are named scalars (macro-expanded), G values
// are named scalars consumed in place, H is folded inline. Nothing can
// be demoted to scratch.
__global__ __launch_bounds__(256) void fourier_interp_kernel(
    const float* __restrict__ y, const float* __restrict__ xnew,
    float* __restrict__ out) {
  const int tid = threadIdx.x;
  const int gid = blockIdx.x * 256 + tid;
  const int h  = gid & 3;
  const int pt = gid >> 2;            // 0..32767
  const int b  = pt >> 12;

  const float2 x2v = ((const float2*)xnew)[pt];
  const Dim d0 = dimcalc(x2v.x * 31.0f);   // rows (i / p)
  const Dim d1 = dimcalc(x2v.y * 31.0f);   // cols (j / q)

  const int p0 = h * 8;
  const float* ybase = y + b * 1024 + p0 * 32;

  float S0r = 0.f, S0i = 0.f, S1r = 0.f, S1i = 0.f;
  float S2r = 0.f, S2i = 0.f, S3r = 0.f, S3i = 0.f;
  float S4r = 0.f, S4i = 0.f, S5r = 0.f, S5i = 0.f;
  float S6r = 0.f, S6i = 0.f, S7r = 0.f, S7i = 0.f;

#define GCOL(c, gr, gi)                                            \
  float gr, gi;                                                    \
  {                                                                \
    float s_ = fmaf(d1.sth, CT[c], -d1.cth * ST[c]);               \
    if ((c) == d1.pstar) s_ = d1.spole;                            \
    const float t_ = d1.K * __builtin_amdgcn_rcpf(s_);             \
    gr = t_ * CT[c];                                               \
    gi = t_ * ST[c];                                               \
  }

#define ROWACC(r, Sr_, Si_)                                        \
  {                                                                \
    const float4 v = *(const float4*)(ybase + (r) * 32 + 4 * q4);  \
    Sr_ = fmaf(v.x, g0r, Sr_); Si_ = fmaf(v.x, g0i, Si_);          \
    Sr_ = fmaf(v.y, g1r, Sr_); Si_ = fmaf(v.y, g1i, Si_);          \
    Sr_ = fmaf(v.z, g2r, Sr_); Si_ = fmaf(v.z, g2i, Si_);          \
    Sr_ = fmaf(v.w, g3r, Sr_); Si_ = fmaf(v.w, g3i, Si_);          \
  }

#pragma unroll
  for (int q4 = 0; q4 < 8; ++q4) {
    GCOL(4 * q4 + 0, g0r, g0i)
    GCOL(4 * q4 + 1, g1r, g1i)
    GCOL(4 * q4 + 2, g2r, g2i)
    GCOL(4 * q4 + 3, g3r, g3i)
    ROWACC(0, S0r, S0i)
    ROWACC(1, S1r, S1i)
    ROWACC(2, S2r, S2i)
    ROWACC(3, S3r, S3i)
    ROWACC(4, S4r, S4i)
    ROWACC(5, S5r, S5i)
    ROWACC(6, S6r, S6i)
    ROWACC(7, S7r, S7i)
  }
#undef GCOL
#undef ROWACC

  // Epilogue: Z = sum_r H_{p0+r} * S_r, H computed inline (no array).
  // cis(pi*p/32) = e4 * cis(pi*r/32), e4 = cis(pi*h/4).
  const float e4r = (h == 0) ? 1.f : (h == 1) ? 0.707106781f
                  : (h == 2) ? 0.f : -0.707106781f;
  const float e4i = (h == 0) ? 0.f : (h == 1) ? 0.707106781f
                  : (h == 2) ? 1.f : 0.707106781f;
  float Zr = 0.f, Zi = 0.f;

#define HROW(r, Sr_, Si_)                                          \
  {                                                                \
    const float Tr = fmaf(e4r, CT[r], -e4i * ST[r]);               \
    const float Ti = fmaf(e4r, ST[r],  e4i * CT[r]);               \
    float s_ = fmaf(d0.sth, Tr, -d0.cth * Ti);                     \
    if (p0 + (r) == d0.pstar) s_ = d0.spole;                       \
    const float t_ = d0.K * __builtin_amdgcn_rcpf(s_);             \
    const float Hr_ = t_ * Tr;                                     \
    const float Hi_ = t_ * Ti;                                     \
    Zr = fmaf(Hr_, Sr_, Zr); Zr = fmaf(-Hi_, Si_, Zr);             \
    Zi = fmaf(Hr_, Si_, Zi); Zi = fmaf(Hi_, Sr_, Zi);              \
  }

  HROW(0, S0r, S0i)
  HROW(1, S1r, S1i)
  HROW(2, S2r, S2i)
  HROW(3, S3r, S3i)
  HROW(4, S4r, S4i)
  HROW(5, S5r, S5i)
  HROW(6, S6r, S6i)
  HROW(7, S7r, S7i)
#undef HROW

  // Combine the 4-lane group, apply unit phases, take Re, scale.
  Zr += __shfl_xor(Zr, 1); Zr += __shfl_xor(Zr, 2);
  Zi += __shfl_xor(Zi, 1); Zi += __shfl_xor(Zi, 2);
  const float Cr = fmaf(d0.Cr, d1.Cr, -d0.Ci * d1.Ci);
  const float Ci = fmaf(d0.Cr, d1.Ci,  d0.Ci * d1.Cr);
  const float res = fmaf(Cr, Zr, -Ci * Zi) * (1.0f / 1024.0f);

  // Pack 16 results into lanes 0..15 of each wave for a coalesced 64B store.
  const int l = tid & 63;
  const float packed = __shfl(res, (l & 15) * 4);
  if (l < 16) {
    const int wbase = (blockIdx.x * 256 + (tid & ~63)) >> 2;
    out[wbase + l] = packed;
  }
}

extern "C" void kernel_launch(void* const* d_in, const int* in_sizes, int n_in,
                              void* d_out, int out_size, void* d_ws, size_t ws_size,
                              hipStream_t stream) {
  const float* y    = (const float*)d_in[0];   // (8, 32, 32) f32
  const float* xnew = (const float*)d_in[1];   // (8, 64, 64, 2) f32
  float* out = (float*)d_out;                  // (8, 64, 64) f32
  (void)d_ws; (void)ws_size;

  // 8 * 4096 points * 4 lanes / 256 threads = 512 blocks
  hipLaunchKernelGGL(fourier_interp_kernel, dim3(512), dim3(256), 0, stream,
                     y, xnew, out);
}

// Round 13
// 60.266 us; speedup vs baseline: 4.0748x; 1.1418x over previous
//
#include <hip/hip_runtime.h>
#include <math.h>

#define PI_F   3.14159265358979f
#define PIO32  0.0981747704246810f   // pi/32

// cos(pi*k/32), sin(pi*k/32), k = 0..31. Only indexed with compile-time
// constants -> fold to instruction literals.
constexpr float CT[32] = {
  1.0f,          0.995184727f,  0.980785280f,  0.956940336f,
  0.923879533f,  0.881921264f,  0.831469612f,  0.773010453f,
  0.707106781f,  0.634393284f,  0.555570233f,  0.471396737f,
  0.382683432f,  0.290284677f,  0.195090322f,  0.0980171403f,
  0.0f,         -0.0980171403f, -0.195090322f, -0.290284677f,
 -0.382683432f, -0.471396737f, -0.555570233f, -0.634393284f,
 -0.707106781f, -0.773010453f, -0.831469612f, -0.881921264f,
 -0.923879533f, -0.956940336f, -0.980785280f, -0.995184727f };
constexpr float ST[32] = {
  0.0f,          0.0980171403f, 0.195090322f,  0.290284677f,
  0.382683432f,  0.471396737f,  0.555570233f,  0.634393284f,
  0.707106781f,  0.773010453f,  0.831469612f,  0.881921264f,
  0.923879533f,  0.956940336f,  0.980785280f,  0.995184727f,
  1.0f,          0.995184727f,  0.980785280f,  0.956940336f,
  0.923879533f,  0.881921264f,  0.831469612f,  0.773010453f,
  0.707106781f,  0.634393284f,  0.555570233f,  0.471396737f,
  0.382683432f,  0.290284677f,  0.195090322f,  0.0980171403f };

struct Dim {
  float K;         // (-1)^{p*} * sin(pi * dstar)
  float Cr, Ci;    // cis((31pi/32) * sp)
  float sth, cth;  // sincos((pi/32) * sp)
  float spole;     // accurate sin((pi/32) * dstar)
  int   pstar;     // nearest grid line
};

__device__ __forceinline__ Dim dimcalc(float sp) {
  Dim d;
  const float ps = rintf(sp);
  d.pstar = (int)ps;
  float dstar = sp - ps;                 // EXACT in fp32 (Sterbenz)
  if (dstar == 0.0f) dstar = 1e-10f;     // removable singularity: ratio -> 32
  const float th = sp * PIO32;           // |th| <= 31pi/32: HW sin range
  d.sth = __sinf(th);
  d.cth = __cosf(th);
  const float pd = PI_F * dstar;         // |pd| <= pi/2
  const float sd = __sinf(pd);
  const float cd = __cosf(pd);
  const float par = (d.pstar & 1) ? -1.0f : 1.0f;
  d.K = par * sd;
  d.Cr = par * fmaf(cd, d.cth, sd * d.sth);
  d.Ci = par * fmaf(sd, d.cth, -cd * d.sth);
  const float x = dstar * PIO32;
  const float x2 = x * x;
  d.spole = x * fmaf(x2, fmaf(x2, 0.00833333333f, -0.166666667f), 1.0f);
  return d;
}

// out[b,n] = (1/1024) * Re( C0*C1 * sum_p H_p sum_q y[p,q] G_q )
//
// COLUMN-SPLIT (r12 evidence: 3 different codegens all ~13-16us, VALUBusy
// 19%, more waves -> slower => shared vector-memory-pipe serialization of
// the 4-distinct-line gather, ~500cyc/load). Lane h of each 4-lane group
// owns columns {4h..4h+3} u {16+4h..16+4h+3}; every float4 load now covers
// ONE 64B line across the group (contiguous + broadcast), not 4 lines.
// H runs over all 32 compile-time rows (CT/ST stay literals); G twiddles
// for runtime-h columns via e8 = cis(pi*h/8): cis(pi(4h+j)/32) = e8*T_j,
// cis(pi(16+4h+j)/32) = i*e8*T_j. Zero arrays; all named scalars.
__global__ __launch_bounds__(256) void fourier_interp_kernel(
    const float* __restrict__ y, const float* __restrict__ xnew,
    float* __restrict__ out) {
  const int tid = threadIdx.x;
  const int gid = blockIdx.x * 256 + tid;
  const int h  = gid & 3;
  const int pt = gid >> 2;            // 0..32767
  const int b  = pt >> 12;

  const float2 x2v = ((const float2*)xnew)[pt];
  const Dim d0 = dimcalc(x2v.x * 31.0f);   // rows (i / p)
  const Dim d1 = dimcalc(x2v.y * 31.0f);   // cols (j / q)

  // e8 = cis(pi*h/8), h in 0..3.
  const float e8r = (h == 0) ? 1.f : (h == 1) ? 0.923879533f
                  : (h == 2) ? 0.707106781f : 0.382683432f;
  const float e8i = (h == 0) ? 0.f : (h == 1) ? 0.382683432f
                  : (h == 2) ? 0.707106781f : 0.923879533f;

  // T_j = e8 * cis(pi*j/32), j = 0..3 (compile-time CT/ST -> literals).
  const float T0r = e8r;                                  // j=0
  const float T0i = e8i;
  const float T1r = fmaf(e8r, CT[1], -e8i * ST[1]);
  const float T1i = fmaf(e8r, ST[1],  e8i * CT[1]);
  const float T2r = fmaf(e8r, CT[2], -e8i * ST[2]);
  const float T2i = fmaf(e8r, ST[2],  e8i * CT[2]);
  const float T3r = fmaf(e8r, CT[3], -e8i * ST[3]);
  const float T3i = fmaf(e8r, ST[3],  e8i * CT[3]);

  // G for the low block c = 4h+j (G = K * cis(pi*c/32) / sin((pi/32)(sp1-c)))
#define GLO(j, Tjr, Tji, gr, gi)                                   \
  float gr, gi;                                                    \
  {                                                                \
    float s_ = fmaf(d1.sth, Tjr, -d1.cth * Tji);                   \
    if (4 * h + (j) == d1.pstar) s_ = d1.spole;                    \
    const float t_ = d1.K * __builtin_amdgcn_rcpf(s_);             \
    gr = t_ * Tjr;                                                 \
    gi = t_ * Tji;                                                 \
  }
  // High block c' = 16+4h+j: twiddle = i*T_j -> (Tr',Ti') = (-Tji, Tjr).
#define GHI(j, Tjr, Tji, gr, gi)                                   \
  float gr, gi;                                                    \
  {                                                                \
    float s_ = -fmaf(d1.sth, Tji, d1.cth * Tjr);                   \
    if (16 + 4 * h + (j) == d1.pstar) s_ = d1.spole;               \
    const float t_ = d1.K * __builtin_amdgcn_rcpf(s_);             \
    gr = -t_ * Tji;                                                \
    gi =  t_ * Tjr;                                                \
  }

  GLO(0, T0r, T0i, gl0r, gl0i)
  GLO(1, T1r, T1i, gl1r, gl1i)
  GLO(2, T2r, T2i, gl2r, gl2i)
  GLO(3, T3r, T3i, gl3r, gl3i)
  GHI(0, T0r, T0i, gh0r, gh0i)
  GHI(1, T1r, T1i, gh1r, gh1i)
  GHI(2, T2r, T2i, gh2r, gh2i)
  GHI(3, T3r, T3i, gh3r, gh3i)
#undef GLO
#undef GHI

  // Main loop: all 32 rows; per row two single-line loads, partial
  // S_r over this lane's 8 columns, H_r (compile-time r) folded in.
  const float* ybase = y + b * 1024 + h * 4;
  float Zr = 0.f, Zi = 0.f;
#pragma unroll
  for (int r = 0; r < 32; ++r) {
    const float4 v0 = *(const float4*)(ybase + r * 32);        // line 1
    const float4 v1 = *(const float4*)(ybase + r * 32 + 16);   // line 2
    float SrA = v0.x * gl0r;  SrA = fmaf(v0.z, gl2r, SrA);
    SrA = fmaf(v1.x, gh0r, SrA); SrA = fmaf(v1.z, gh2r, SrA);
    float SrB = v0.y * gl1r;  SrB = fmaf(v0.w, gl3r, SrB);
    SrB = fmaf(v1.y, gh1r, SrB); SrB = fmaf(v1.w, gh3r, SrB);
    float SiA = v0.x * gl0i;  SiA = fmaf(v0.z, gl2i, SiA);
    SiA = fmaf(v1.x, gh0i, SiA); SiA = fmaf(v1.z, gh2i, SiA);
    float SiB = v0.y * gl1i;  SiB = fmaf(v0.w, gl3i, SiB);
    SiB = fmaf(v1.y, gh1i, SiB); SiB = fmaf(v1.w, gh3i, SiB);
    const float Sr = SrA + SrB;
    const float Si = SiA + SiB;
    // H_r = K0 * cis(pi*r/32) / sin((pi/32)(sp0 - r)), r compile-time.
    float s_ = fmaf(d0.sth, CT[r], -d0.cth * ST[r]);
    if (r == d0.pstar) s_ = d0.spole;
    const float t_ = d0.K * __builtin_amdgcn_rcpf(s_);
    const float Hr = t_ * CT[r];
    const float Hi = t_ * ST[r];
    Zr = fmaf(Hr, Sr, Zr); Zr = fmaf(-Hi, Si, Zr);
    Zi = fmaf(Hr, Si, Zi); Zi = fmaf(Hi, Sr, Zi);
  }

  // Combine the 4-lane group, apply unit phases, take Re, scale.
  Zr += __shfl_xor(Zr, 1); Zr += __shfl_xor(Zr, 2);
  Zi += __shfl_xor(Zi, 1); Zi += __shfl_xor(Zi, 2);
  const float Cr = fmaf(d0.Cr, d1.Cr, -d0.Ci * d1.Ci);
  const float Ci = fmaf(d0.Cr, d1.Ci,  d0.Ci * d1.Cr);
  const float res = fmaf(Cr, Zr, -Ci * Zi) * (1.0f / 1024.0f);

  // Pack 16 results into lanes 0..15 of each wave for a coalesced 64B store.
  const int l = tid & 63;
  const float packed = __shfl(res, (l & 15) * 4);
  if (l < 16) {
    const int wbase = (blockIdx.x * 256 + (tid & ~63)) >> 2;
    out[wbase + l] = packed;
  }
}

extern "C" void kernel_launch(void* const* d_in, const int* in_sizes, int n_in,
                              void* d_out, int out_size, void* d_ws, size_t ws_size,
                              hipStream_t stream) {
  const float* y    = (const float*)d_in[0];   // (8, 32, 32) f32
  const float* xnew = (const float*)d_in[1];   // (8, 64, 64, 2) f32
  float* out = (float*)d_out;                  // (8, 64, 64) f32
  (void)d_ws; (void)ws_size;

  // 8 * 4096 points * 4 lanes / 256 threads = 512 blocks
  hipLaunchKernelGGL(fourier_interp_kernel, dim3(512), dim3(256), 0, stream,
                     y, xnew, out);
}

// Round 14
// 58.879 us; speedup vs baseline: 4.1708x; 1.0236x over previous
//
#include <hip/hip_runtime.h>
#include <math.h>

#define PI_F   3.14159265358979f
#define PIO32  0.0981747704246810f   // pi/32

// cos(pi*k/32), sin(pi*k/32), k = 0..31. Only compile-time indexed.
constexpr float CT[32] = {
  1.0f,          0.995184727f,  0.980785280f,  0.956940336f,
  0.923879533f,  0.881921264f,  0.831469612f,  0.773010453f,
  0.707106781f,  0.634393284f,  0.555570233f,  0.471396737f,
  0.382683432f,  0.290284677f,  0.195090322f,  0.0980171403f,
  0.0f,         -0.0980171403f, -0.195090322f, -0.290284677f,
 -0.382683432f, -0.471396737f, -0.555570233f, -0.634393284f,
 -0.707106781f, -0.773010453f, -0.831469612f, -0.881921264f,
 -0.923879533f, -0.956940336f, -0.980785280f, -0.995184727f };
constexpr float ST[32] = {
  0.0f,          0.0980171403f, 0.195090322f,  0.290284677f,
  0.382683432f,  0.471396737f,  0.555570233f,  0.634393284f,
  0.707106781f,  0.773010453f,  0.831469612f,  0.881921264f,
  0.923879533f,  0.956940336f,  0.980785280f,  0.995184727f,
  1.0f,          0.995184727f,  0.980785280f,  0.956940336f,
  0.923879533f,  0.881921264f,  0.831469612f,  0.773010453f,
  0.707106781f,  0.634393284f,  0.555570233f,  0.471396737f,
  0.382683432f,  0.290284677f,  0.195090322f,  0.0980171403f };

struct Dim {
  float K;         // (-1)^{p*} * sin(pi * dstar)
  float Cr, Ci;    // cis((31pi/32) * sp)
  float sth, cth;  // sincos((pi/32) * sp)
  float spole;     // accurate sin((pi/32) * dstar)
  int   pstar;     // nearest grid line
};

__device__ __forceinline__ Dim dimcalc(float sp) {
  Dim d;
  const float ps = rintf(sp);
  d.pstar = (int)ps;
  float dstar = sp - ps;                 // EXACT in fp32 (Sterbenz)
  if (dstar == 0.0f) dstar = 1e-10f;     // removable singularity: ratio -> 32
  const float th = sp * PIO32;           // HW sin range
  d.sth = __sinf(th);
  d.cth = __cosf(th);
  const float pd = PI_F * dstar;         // |pd| <= pi/2
  const float sd = __sinf(pd);
  const float cd = __cosf(pd);
  const float par = (d.pstar & 1) ? -1.0f : 1.0f;
  d.K = par * sd;
  d.Cr = par * fmaf(cd, d.cth, sd * d.sth);
  d.Ci = par * fmaf(sd, d.cth, -cd * d.sth);
  const float x = dstar * PIO32;
  const float x2 = x * x;
  d.spole = x * fmaf(x2, fmaf(x2, 0.00833333333f, -0.166666667f), 1.0f);
  return d;
}

// 8 lanes/point: lane (h,u) owns cols {4h..4h+3} u {16+4h..16+4h+3} (same
// single-line float4 loads as r13) and rows 16u..16u+15. Row-half twiddle
// i^u factors OUT of the loop: rotate (sth,cth) once for u=1 and apply i^u
// to the partial Z once — per-row cost identical to r13, per-lane work
// ~0.6x, waves/SIMD 2 -> 4 (r13 evidence: memory pipe fixed, 6.8us vs
// ~2us issue floor => latency-bound at 2 waves/SIMD).
__global__ __launch_bounds__(256) void fourier_interp_kernel(
    const float* __restrict__ y, const float* __restrict__ xnew,
    float* __restrict__ out) {
  const int tid = threadIdx.x;
  const int gid = blockIdx.x * 256 + tid;
  const int h  = gid & 3;            // column block
  const int u  = (gid >> 2) & 1;     // row half
  const int pt = gid >> 3;           // 0..32767
  const int b  = pt >> 12;

  const float2 x2v = ((const float2*)xnew)[pt];
  const Dim d0 = dimcalc(x2v.x * 31.0f);   // rows (i / p)
  const Dim d1 = dimcalc(x2v.y * 31.0f);   // cols (j / q)

  // e8 = cis(pi*h/8), h in 0..3.
  const float e8r = (h == 0) ? 1.f : (h == 1) ? 0.923879533f
                  : (h == 2) ? 0.707106781f : 0.382683432f;
  const float e8i = (h == 0) ? 0.f : (h == 1) ? 0.382683432f
                  : (h == 2) ? 0.707106781f : 0.923879533f;

  // T_j = e8 * cis(pi*j/32), j = 0..3 (CT/ST literals).
  const float T0r = e8r;
  const float T0i = e8i;
  const float T1r = fmaf(e8r, CT[1], -e8i * ST[1]);
  const float T1i = fmaf(e8r, ST[1],  e8i * CT[1]);
  const float T2r = fmaf(e8r, CT[2], -e8i * ST[2]);
  const float T2i = fmaf(e8r, ST[2],  e8i * CT[2]);
  const float T3r = fmaf(e8r, CT[3], -e8i * ST[3]);
  const float T3i = fmaf(e8r, ST[3],  e8i * CT[3]);

#define GLO(j, Tjr, Tji, gr, gi)                                   \
  float gr, gi;                                                    \
  {                                                                \
    float s_ = fmaf(d1.sth, Tjr, -d1.cth * Tji);                   \
    if (4 * h + (j) == d1.pstar) s_ = d1.spole;                    \
    const float t_ = d1.K * __builtin_amdgcn_rcpf(s_);             \
    gr = t_ * Tjr;                                                 \
    gi = t_ * Tji;                                                 \
  }
#define GHI(j, Tjr, Tji, gr, gi)                                   \
  float gr, gi;                                                    \
  {                                                                \
    float s_ = -fmaf(d1.sth, Tji, d1.cth * Tjr);                   \
    if (16 + 4 * h + (j) == d1.pstar) s_ = d1.spole;               \
    const float t_ = d1.K * __builtin_amdgcn_rcpf(s_);             \
    gr = -t_ * Tji;                                                \
    gi =  t_ * Tjr;                                                \
  }

  GLO(0, T0r, T0i, gl0r, gl0i)
  GLO(1, T1r, T1i, gl1r, gl1i)
  GLO(2, T2r, T2i, gl2r, gl2i)
  GLO(3, T3r, T3i, gl3r, gl3i)
  GHI(0, T0r, T0i, gh0r, gh0i)
  GHI(1, T1r, T1i, gh1r, gh1i)
  GHI(2, T2r, T2i, gh2r, gh2i)
  GHI(3, T3r, T3i, gh3r, gh3i)
#undef GLO
#undef GHI

  // Row-half rotation: sin/cos((pi/32)sp0 - u*pi/2):
  //   u=0: (sth, cth); u=1: (-cth, sth).  Pole row index shifts by 16u.
  const float sthu = u ? -d0.cth : d0.sth;
  const float cthu = u ?  d0.sth : d0.cth;
  const int pstar_u = d0.pstar - 16 * u;

  // Main loop: 16 rows (rr = 0..15, global row = 16u+rr).
  const float* ybase = y + b * 1024 + u * 512 + h * 4;
  float Zr = 0.f, Zi = 0.f;
#pragma unroll
  for (int rr = 0; rr < 16; ++rr) {
    const float4 v0 = *(const float4*)(ybase + rr * 32);        // line 1
    const float4 v1 = *(const float4*)(ybase + rr * 32 + 16);   // line 2
    float SrA = v0.x * gl0r;  SrA = fmaf(v0.z, gl2r, SrA);
    SrA = fmaf(v1.x, gh0r, SrA); SrA = fmaf(v1.z, gh2r, SrA);
    float SrB = v0.y * gl1r;  SrB = fmaf(v0.w, gl3r, SrB);
    SrB = fmaf(v1.y, gh1r, SrB); SrB = fmaf(v1.w, gh3r, SrB);
    float SiA = v0.x * gl0i;  SiA = fmaf(v0.z, gl2i, SiA);
    SiA = fmaf(v1.x, gh0i, SiA); SiA = fmaf(v1.z, gh2i, SiA);
    float SiB = v0.y * gl1i;  SiB = fmaf(v0.w, gl3i, SiB);
    SiB = fmaf(v1.y, gh1i, SiB); SiB = fmaf(v1.w, gh3i, SiB);
    const float Sr = SrA + SrB;
    const float Si = SiA + SiB;
    // H'_rr = K0 * cis(pi*rr/32) / sin((pi/32)sp0 - u*pi/2 - pi*rr/32)
    float s_ = fmaf(sthu, CT[rr], -cthu * ST[rr]);
    if (rr == pstar_u) s_ = d0.spole;
    const float t_ = d0.K * __builtin_amdgcn_rcpf(s_);
    const float Hr = t_ * CT[rr];
    const float Hi = t_ * ST[rr];
    Zr = fmaf(Hr, Sr, Zr); Zr = fmaf(-Hi, Si, Zr);
    Zi = fmaf(Hr, Si, Zi); Zi = fmaf(Hi, Sr, Zi);
  }

  // Apply i^u to the partial: u=1 -> (Zr,Zi) = (-Zi, Zr).
  const float Zr_f = u ? -Zi : Zr;
  const float Zi_f = u ?  Zr : Zi;

  // Combine the 8-lane group, apply unit phases, take Re, scale.
  float Ar = Zr_f, Ai = Zi_f;
  Ar += __shfl_xor(Ar, 1); Ar += __shfl_xor(Ar, 2); Ar += __shfl_xor(Ar, 4);
  Ai += __shfl_xor(Ai, 1); Ai += __shfl_xor(Ai, 2); Ai += __shfl_xor(Ai, 4);
  const float Cr = fmaf(d0.Cr, d1.Cr, -d0.Ci * d1.Ci);
  const float Ci = fmaf(d0.Cr, d1.Ci,  d0.Ci * d1.Cr);
  const float res = fmaf(Cr, Ar, -Ci * Ai) * (1.0f / 1024.0f);

  // Pack 8 results into lanes 0..7 of each wave for a coalesced store.
  const int l = tid & 63;
  const float packed = __shfl(res, (l & 7) * 8);
  if (l < 8) {
    const int wbase = (blockIdx.x * 256 + (tid & ~63)) >> 3;
    out[wbase + l] = packed;
  }
}

extern "C" void kernel_launch(void* const* d_in, const int* in_sizes, int n_in,
                              void* d_out, int out_size, void* d_ws, size_t ws_size,
                              hipStream_t stream) {
  const float* y    = (const float*)d_in[0];   // (8, 32, 32) f32
  const float* xnew = (const float*)d_in[1];   // (8, 64, 64, 2) f32
  float* out = (float*)d_out;                  // (8, 64, 64) f32
  (void)d_ws; (void)ws_size;

  // 8 * 4096 points * 8 lanes / 256 threads = 1024 blocks
  hipLaunchKernelGGL(fourier_interp_kernel, dim3(1024), dim3(256), 0, stream,
                     y, xnew, out);
}